// Round 1
// baseline (516.038 us; speedup 1.0000x reference)
//
#include <hip/hip_runtime.h>
#include <hip/hip_bf16.h>

#define D_MODEL 1024
#define N_HEADS 16
#define D_HEAD  64
#define BATCH   4
#define SEQ     2048

typedef __attribute__((ext_vector_type(8))) short short8;
typedef __attribute__((ext_vector_type(8))) unsigned short ushort8;
typedef __attribute__((ext_vector_type(4))) float f32x4;

__device__ inline unsigned short f2bf(float f) {
  unsigned int u = __builtin_bit_cast(unsigned int, f);
  u += 0x7fffu + ((u >> 16) & 1u);
  return (unsigned short)(u >> 16);
}

__device__ inline f32x4 mfma_bf16(short8 a, short8 b, f32x4 c) {
  return __builtin_amdgcn_mfma_f32_16x16x32_bf16(a, b, c, 0, 0, 0);
}

// ---------------- fp32 -> bf16 conversion ----------------
__global__ void cvt_kernel(const float* __restrict__ src,
                           unsigned short* __restrict__ dst, int n) {
  int i = (blockIdx.x * 256 + threadIdx.x) * 8;
  if (i >= n) return;
  float4 a = *reinterpret_cast<const float4*>(src + i);
  float4 b = *reinterpret_cast<const float4*>(src + i + 4);
  ushort8 o;
  o[0] = f2bf(a.x); o[1] = f2bf(a.y); o[2] = f2bf(a.z); o[3] = f2bf(a.w);
  o[4] = f2bf(b.x); o[5] = f2bf(b.y); o[6] = f2bf(b.z); o[7] = f2bf(b.w);
  *reinterpret_cast<ushort8*>(dst + i) = o;
}

// ---------------- swizzled global->LDS staging ----------------
// Tiles have 64-bf16 (128B) rows. LDS layout is linear [rows][64] with the
// byte-column XOR-swizzled by ((row&7)<<4) applied on the *global source*
// (rule: linear dest + inverse-swz source + swz on read).
template<int NBYTES>
__device__ inline void stage_swz(const unsigned short* g0, int g_stride_elems,
                                 unsigned short* lds0, int tid) {
#pragma unroll
  for (int it = 0; it < NBYTES / 4096; ++it) {
    int o = it * 4096 + tid * 16;
    int r = o >> 7;
    int cb = (o & 127) ^ ((r & 7) << 4);
    unsigned short* g = const_cast<unsigned short*>(g0) +
                        (size_t)r * g_stride_elems + (cb >> 1);
    unsigned short* l = lds0 + (o >> 1);
    __builtin_amdgcn_global_load_lds((__attribute__((address_space(1))) void*)g,
                                     (__attribute__((address_space(3))) void*)l,
                                     16, 0, 0);
  }
}

// swizzled LDS fragment read (16B): row-stride fixed 128B
__device__ inline short8 frag_ld(const unsigned short* tile, int row, int col_el) {
  int cb = (col_el << 1) ^ ((row & 7) << 4);
  return *reinterpret_cast<const short8*>(
      reinterpret_cast<const char*>(tile) + row * 128 + cb);
}

// ---------------- QKV projection GEMM ----------------
// y[m,e] = sum_k x[m,k] * w[e,k]. z=0 -> Q (scaled 1/8, [B,H,S,Dh]),
// z=1 -> K ([B,H,S,Dh]), z=2 -> V transposed ([B,H,Dh,S]) via swapped MFMA.
__launch_bounds__(256, 2)
__global__ void qkv_gemm(const unsigned short* __restrict__ xb,
                         const unsigned short* __restrict__ wb,
                         unsigned short* __restrict__ Qo,
                         unsigned short* __restrict__ Ko,
                         unsigned short* __restrict__ Vt) {
  __shared__ __align__(16) unsigned short As[128][64];
  __shared__ __align__(16) unsigned short Bs[128][64];
  const int z = blockIdx.z;
  const int m0 = blockIdx.y * 128;
  const int n0 = blockIdx.x * 128;
  const int tid = threadIdx.x;
  const int lane = tid & 63;
  const int wv = tid >> 6;
  const int wr = wv >> 1, wc = wv & 1;
  const int lrow = lane & 15;
  const int lk8 = (lane >> 4) << 3;
  const unsigned short* w = wb + (size_t)z * D_MODEL * D_MODEL;

  f32x4 acc[4][4];
  const f32x4 zero = {0.f, 0.f, 0.f, 0.f};
#pragma unroll
  for (int i = 0; i < 4; ++i)
#pragma unroll
    for (int j = 0; j < 4; ++j) acc[i][j] = zero;

  for (int k0 = 0; k0 < D_MODEL; k0 += 64) {
    __syncthreads();
    stage_swz<16384>(xb + (size_t)m0 * D_MODEL + k0, D_MODEL, &As[0][0], tid);
    stage_swz<16384>(w  + (size_t)n0 * D_MODEL + k0, D_MODEL, &Bs[0][0], tid);
    __syncthreads();
#pragma unroll
    for (int ks = 0; ks < 2; ++ks) {
      short8 af[4], bfr[4];
#pragma unroll
      for (int mi = 0; mi < 4; ++mi)
        af[mi] = frag_ld(&As[0][0], wr * 64 + mi * 16 + lrow, ks * 32 + lk8);
#pragma unroll
      for (int ni = 0; ni < 4; ++ni)
        bfr[ni] = frag_ld(&Bs[0][0], wc * 64 + ni * 16 + lrow, ks * 32 + lk8);
      if (z != 2) {
#pragma unroll
        for (int mi = 0; mi < 4; ++mi)
#pragma unroll
          for (int ni = 0; ni < 4; ++ni)
            acc[mi][ni] = mfma_bf16(af[mi], bfr[ni], acc[mi][ni]);
      } else {
#pragma unroll
        for (int ni = 0; ni < 4; ++ni)
#pragma unroll
          for (int mi = 0; mi < 4; ++mi)
            acc[ni][mi] = mfma_bf16(bfr[ni], af[mi], acc[ni][mi]);
      }
    }
  }

  const int lrr = (lane >> 4) << 2;
  if (z != 2) {
    unsigned short* dst = (z == 0) ? Qo : Ko;
    const float scale = (z == 0) ? 0.125f : 1.0f;
#pragma unroll
    for (int mi = 0; mi < 4; ++mi)
#pragma unroll
      for (int ni = 0; ni < 4; ++ni)
#pragma unroll
        for (int r = 0; r < 4; ++r) {
          int m = m0 + wr * 64 + mi * 16 + lrr + r;
          int e = n0 + wc * 64 + ni * 16 + lrow;
          int b = m >> 11, s = m & (SEQ - 1);
          int h = e >> 6, dh = e & 63;
          dst[((size_t)(b * N_HEADS + h) * SEQ + s) * D_HEAD + dh] =
              f2bf(acc[mi][ni][r] * scale);
        }
  } else {
#pragma unroll
    for (int ni = 0; ni < 4; ++ni)
#pragma unroll
      for (int mi = 0; mi < 4; ++mi)
#pragma unroll
        for (int r = 0; r < 4; ++r) {
          int e = n0 + wc * 64 + ni * 16 + lrr + r;
          int m = m0 + wr * 64 + mi * 16 + lrow;
          int b = m >> 11, s = m & (SEQ - 1);
          int h = e >> 6, dh = e & 63;
          Vt[((size_t)(b * N_HEADS + h) * D_HEAD + dh) * SEQ + s] =
              f2bf(acc[ni][mi][r]);
        }
  }
}

// ---------------- flash attention with additive bias ----------------
__launch_bounds__(256, 2)
__global__ void attn_kernel(const unsigned short* __restrict__ Q,
                            const unsigned short* __restrict__ K,
                            const unsigned short* __restrict__ Vt,
                            const float* __restrict__ bias,
                            unsigned short* __restrict__ ctx) {
  __shared__ __align__(16) unsigned short Qs[64][64];
  __shared__ __align__(16) unsigned short Ks[64][64];
  __shared__ __align__(16) unsigned short Vs[64][64];
  __shared__ __align__(16) unsigned short Ps[4][16][72];

  const int bh = blockIdx.y;
  const int b = bh >> 4, h = bh & (N_HEADS - 1);
  const int q0 = blockIdx.x * 64;
  const int tid = threadIdx.x, lane = tid & 63, wv = tid >> 6;
  const int lrow = lane & 15;
  const int lk8 = (lane >> 4) << 3;
  const int lrr = (lane >> 4) << 2;

  const size_t qk_base = (size_t)bh * SEQ * D_HEAD;

  stage_swz<8192>(Q + qk_base + (size_t)q0 * D_HEAD, D_HEAD, &Qs[0][0], tid);
  __syncthreads();
  short8 aq[2];
#pragma unroll
  for (int ks = 0; ks < 2; ++ks)
    aq[ks] = frag_ld(&Qs[0][0], wv * 16 + lrow, ks * 32 + lk8);

  float m_run[4], l_run[4];
  f32x4 o_acc[4];
  const f32x4 zero = {0.f, 0.f, 0.f, 0.f};
#pragma unroll
  for (int r = 0; r < 4; ++r) { m_run[r] = -1e30f; l_run[r] = 0.f; }
#pragma unroll
  for (int dt = 0; dt < 4; ++dt) o_acc[dt] = zero;

  const float* brow =
      bias + (size_t)h * SEQ * SEQ + (size_t)(q0 + wv * 16 + lrr) * SEQ;

  for (int kt = 0; kt < 32; ++kt) {
    const int kv0 = kt * 64;
    __syncthreads();
    stage_swz<8192>(K + qk_base + (size_t)kv0 * D_HEAD, D_HEAD, &Ks[0][0], tid);
    stage_swz<8192>(Vt + (size_t)bh * D_HEAD * SEQ + kv0, SEQ, &Vs[0][0], tid);
    __syncthreads();

    f32x4 s_acc[4];
#pragma unroll
    for (int nt = 0; nt < 4; ++nt) s_acc[nt] = zero;
#pragma unroll
    for (int ks = 0; ks < 2; ++ks)
#pragma unroll
      for (int nt = 0; nt < 4; ++nt) {
        short8 kf = frag_ld(&Ks[0][0], nt * 16 + lrow, ks * 32 + lk8);
        s_acc[nt] = mfma_bf16(aq[ks], kf, s_acc[nt]);
      }

    float sv[4][4];
#pragma unroll
    for (int nt = 0; nt < 4; ++nt)
#pragma unroll
      for (int r = 0; r < 4; ++r)
        sv[nt][r] = s_acc[nt][r] +
                    brow[(size_t)r * SEQ + kv0 + nt * 16 + lrow];

#pragma unroll
    for (int r = 0; r < 4; ++r) {
      float mx = fmaxf(fmaxf(sv[0][r], sv[1][r]), fmaxf(sv[2][r], sv[3][r]));
#pragma unroll
      for (int msk = 1; msk < 16; msk <<= 1) mx = fmaxf(mx, __shfl_xor(mx, msk));
      float mnew = fmaxf(m_run[r], mx);
      float corr = __expf(m_run[r] - mnew);
      float rs = 0.f;
#pragma unroll
      for (int nt = 0; nt < 4; ++nt) {
        float p = __expf(sv[nt][r] - mnew);
        sv[nt][r] = p;
        rs += p;
      }
#pragma unroll
      for (int msk = 1; msk < 16; msk <<= 1) rs += __shfl_xor(rs, msk);
      l_run[r] = l_run[r] * corr + rs;
      m_run[r] = mnew;
#pragma unroll
      for (int dt = 0; dt < 4; ++dt) o_acc[dt][r] *= corr;
    }

    // P -> LDS (per-wave private region; same-wave DS ordering suffices)
#pragma unroll
    for (int nt = 0; nt < 4; ++nt)
#pragma unroll
      for (int r = 0; r < 4; ++r)
        Ps[wv][lrr + r][nt * 16 + lrow] = f2bf(sv[nt][r]);

#pragma unroll
    for (int ks = 0; ks < 2; ++ks) {
      const unsigned short* prow = &Ps[wv][lrow][0];
      short8 pf = *reinterpret_cast<const short8*>(prow + ks * 32 + lk8);
#pragma unroll
      for (int dt = 0; dt < 4; ++dt) {
        short8 vf = frag_ld(&Vs[0][0], dt * 16 + lrow, ks * 32 + lk8);
        o_acc[dt] = mfma_bf16(pf, vf, o_acc[dt]);
      }
    }
  }

#pragma unroll
  for (int dt = 0; dt < 4; ++dt)
#pragma unroll
    for (int r = 0; r < 4; ++r) {
      int qs = q0 + wv * 16 + lrr + r;
      float inv = 1.0f / l_run[r];
      ctx[((size_t)(b * SEQ) + qs) * D_MODEL + h * 64 + dt * 16 + lrow] =
          f2bf(o_acc[dt][r] * inv);
    }
}

// ---------------- output projection GEMM (+bias, fp32 out) ----------------
__launch_bounds__(256, 2)
__global__ void out_gemm(const unsigned short* __restrict__ cb,
                         const unsigned short* __restrict__ wo,
                         const float* __restrict__ bo,
                         float* __restrict__ out) {
  __shared__ __align__(16) unsigned short As[128][64];
  __shared__ __align__(16) unsigned short Bs[128][64];
  const int m0 = blockIdx.y * 128;
  const int n0 = blockIdx.x * 128;
  const int tid = threadIdx.x;
  const int lane = tid & 63;
  const int wv = tid >> 6;
  const int wr = wv >> 1, wc = wv & 1;
  const int lrow = lane & 15;
  const int lk8 = (lane >> 4) << 3;

  f32x4 acc[4][4];
  const f32x4 zero = {0.f, 0.f, 0.f, 0.f};
#pragma unroll
  for (int i = 0; i < 4; ++i)
#pragma unroll
    for (int j = 0; j < 4; ++j) acc[i][j] = zero;

  for (int k0 = 0; k0 < D_MODEL; k0 += 64) {
    __syncthreads();
    stage_swz<16384>(cb + (size_t)m0 * D_MODEL + k0, D_MODEL, &As[0][0], tid);
    stage_swz<16384>(wo + (size_t)n0 * D_MODEL + k0, D_MODEL, &Bs[0][0], tid);
    __syncthreads();
#pragma unroll
    for (int ks = 0; ks < 2; ++ks) {
      short8 af[4], bfr[4];
#pragma unroll
      for (int mi = 0; mi < 4; ++mi)
        af[mi] = frag_ld(&As[0][0], wr * 64 + mi * 16 + lrow, ks * 32 + lk8);
#pragma unroll
      for (int ni = 0; ni < 4; ++ni)
        bfr[ni] = frag_ld(&Bs[0][0], wc * 64 + ni * 16 + lrow, ks * 32 + lk8);
#pragma unroll
      for (int mi = 0; mi < 4; ++mi)
#pragma unroll
        for (int ni = 0; ni < 4; ++ni)
          acc[mi][ni] = mfma_bf16(af[mi], bfr[ni], acc[mi][ni]);
    }
  }

  const int lrr = (lane >> 4) << 2;
#pragma unroll
  for (int mi = 0; mi < 4; ++mi)
#pragma unroll
    for (int ni = 0; ni < 4; ++ni)
#pragma unroll
      for (int r = 0; r < 4; ++r) {
        int m = m0 + wr * 64 + mi * 16 + lrr + r;
        int e = n0 + wc * 64 + ni * 16 + lrow;
        out[(size_t)m * D_MODEL + e] = acc[mi][ni][r] + bo[e];
      }
}

extern "C" void kernel_launch(void* const* d_in, const int* in_sizes, int n_in,
                              void* d_out, int out_size, void* d_ws, size_t ws_size,
                              hipStream_t stream) {
  const float* x    = (const float*)d_in[0];
  const float* bias = (const float*)d_in[1];
  const float* w_q  = (const float*)d_in[2];
  const float* w_k  = (const float*)d_in[3];
  const float* w_v  = (const float*)d_in[4];
  const float* w_o  = (const float*)d_in[5];
  const float* b_o  = (const float*)d_in[6];
  float* out = (float*)d_out;

  const size_t NX = (size_t)BATCH * SEQ * D_MODEL;       // 8388608
  const size_t NW = (size_t)D_MODEL * D_MODEL;           // 1048576

  unsigned short* xb    = (unsigned short*)d_ws;
  unsigned short* wqkvb = xb + NX;
  unsigned short* wob   = wqkvb + 3 * NW;
  unsigned short* Qb    = wob + NW;
  unsigned short* Kb    = Qb + NX;
  unsigned short* Vtb   = Kb + NX;
  unsigned short* ctxb  = Vtb + NX;

  cvt_kernel<<<(int)(NX / 2048), 256, 0, stream>>>(x, xb, (int)NX);
  cvt_kernel<<<(int)(NW / 2048), 256, 0, stream>>>(w_q, wqkvb, (int)NW);
  cvt_kernel<<<(int)(NW / 2048), 256, 0, stream>>>(w_k, wqkvb + NW, (int)NW);
  cvt_kernel<<<(int)(NW / 2048), 256, 0, stream>>>(w_v, wqkvb + 2 * NW, (int)NW);
  cvt_kernel<<<(int)(NW / 2048), 256, 0, stream>>>(w_o, wob, (int)NW);

  qkv_gemm<<<dim3(8, 64, 3), 256, 0, stream>>>(xb, wqkvb, Qb, Kb, Vtb);
  attn_kernel<<<dim3(32, 64), 256, 0, stream>>>(Qb, Kb, Vtb, bias, ctxb);
  out_gemm<<<dim3(8, 64), 256, 0, stream>>>(ctxb, wob, b_o, out);
}

// Round 2
// 355.986 us; speedup vs baseline: 1.4496x; 1.4496x over previous
//
#include <hip/hip_runtime.h>
#include <hip/hip_bf16.h>

#define D_MODEL 1024
#define N_HEADS 16
#define D_HEAD  64
#define BATCH   4
#define SEQ     2048

typedef __attribute__((ext_vector_type(8))) short short8;
typedef __attribute__((ext_vector_type(8))) unsigned short ushort8;
typedef __attribute__((ext_vector_type(4))) unsigned short ushort4v;
typedef __attribute__((ext_vector_type(4))) float f32x4;

__device__ inline unsigned short f2bf(float f) {
  unsigned int u = __builtin_bit_cast(unsigned int, f);
  u += 0x7fffu + ((u >> 16) & 1u);
  return (unsigned short)(u >> 16);
}

__device__ inline f32x4 mfma_bf16(short8 a, short8 b, f32x4 c) {
  return __builtin_amdgcn_mfma_f32_16x16x32_bf16(a, b, c, 0, 0, 0);
}

// ---------------- fp32 -> bf16 conversion ----------------
__global__ void cvt_kernel(const float* __restrict__ src,
                           unsigned short* __restrict__ dst, int n) {
  int i = (blockIdx.x * 256 + threadIdx.x) * 8;
  if (i >= n) return;
  float4 a = *reinterpret_cast<const float4*>(src + i);
  float4 b = *reinterpret_cast<const float4*>(src + i + 4);
  ushort8 o;
  o[0] = f2bf(a.x); o[1] = f2bf(a.y); o[2] = f2bf(a.z); o[3] = f2bf(a.w);
  o[4] = f2bf(b.x); o[5] = f2bf(b.y); o[6] = f2bf(b.z); o[7] = f2bf(b.w);
  *reinterpret_cast<ushort8*>(dst + i) = o;
}

// ---------------- swizzled global->LDS staging ----------------
// Tiles have 64-bf16 (128B) rows. LDS layout is linear [rows][64] with the
// byte-column XOR-swizzled by ((row&7)<<4) applied on the *global source*
// (rule: linear dest + inverse-swz source + swz on read).
template<int NBYTES>
__device__ inline void stage_swz(const unsigned short* g0, int g_stride_elems,
                                 unsigned short* lds0, int tid) {
#pragma unroll
  for (int it = 0; it < NBYTES / 4096; ++it) {
    int o = it * 4096 + tid * 16;
    int r = o >> 7;
    int cb = (o & 127) ^ ((r & 7) << 4);
    unsigned short* g = const_cast<unsigned short*>(g0) +
                        (size_t)r * g_stride_elems + (cb >> 1);
    unsigned short* l = lds0 + (o >> 1);
    __builtin_amdgcn_global_load_lds((__attribute__((address_space(1))) void*)g,
                                     (__attribute__((address_space(3))) void*)l,
                                     16, 0, 0);
  }
}

// swizzled LDS fragment read (16B): row-stride fixed 128B
__device__ inline short8 frag_ld(const unsigned short* tile, int row, int col_el) {
  int cb = (col_el << 1) ^ ((row & 7) << 4);
  return *reinterpret_cast<const short8*>(
      reinterpret_cast<const char*>(tile) + row * 128 + cb);
}

// ---------------- QKV projection GEMM ----------------
// y[m,e] = sum_k x[m,k] * w[e,k]. z=0 -> Q (scaled 1/8, [B,H,S,Dh]),
// z=1 -> K ([B,H,S,Dh]), z=2 -> V transposed ([B,H,Dh,S]) via swapped MFMA.
__launch_bounds__(256, 2)
__global__ void qkv_gemm(const unsigned short* __restrict__ xb,
                         const unsigned short* __restrict__ wb,
                         unsigned short* __restrict__ Qo,
                         unsigned short* __restrict__ Ko,
                         unsigned short* __restrict__ Vt) {
  __shared__ __align__(16) unsigned short As[128][64];
  __shared__ __align__(16) unsigned short Bs[128][64];
  const int z = blockIdx.z;
  const int m0 = blockIdx.y * 128;
  const int n0 = blockIdx.x * 128;
  const int tid = threadIdx.x;
  const int lane = tid & 63;
  const int wv = tid >> 6;
  const int wr = wv >> 1, wc = wv & 1;
  const int lrow = lane & 15;
  const int lk8 = (lane >> 4) << 3;
  const unsigned short* w = wb + (size_t)z * D_MODEL * D_MODEL;

  f32x4 acc[4][4];
  const f32x4 zero = {0.f, 0.f, 0.f, 0.f};
#pragma unroll
  for (int i = 0; i < 4; ++i)
#pragma unroll
    for (int j = 0; j < 4; ++j) acc[i][j] = zero;

  for (int k0 = 0; k0 < D_MODEL; k0 += 64) {
    __syncthreads();
    stage_swz<16384>(xb + (size_t)m0 * D_MODEL + k0, D_MODEL, &As[0][0], tid);
    stage_swz<16384>(w  + (size_t)n0 * D_MODEL + k0, D_MODEL, &Bs[0][0], tid);
    __syncthreads();
#pragma unroll
    for (int ks = 0; ks < 2; ++ks) {
      short8 af[4], bfr[4];
#pragma unroll
      for (int mi = 0; mi < 4; ++mi)
        af[mi] = frag_ld(&As[0][0], wr * 64 + mi * 16 + lrow, ks * 32 + lk8);
#pragma unroll
      for (int ni = 0; ni < 4; ++ni)
        bfr[ni] = frag_ld(&Bs[0][0], wc * 64 + ni * 16 + lrow, ks * 32 + lk8);
      if (z != 2) {
#pragma unroll
        for (int mi = 0; mi < 4; ++mi)
#pragma unroll
          for (int ni = 0; ni < 4; ++ni)
            acc[mi][ni] = mfma_bf16(af[mi], bfr[ni], acc[mi][ni]);
      } else {
#pragma unroll
        for (int ni = 0; ni < 4; ++ni)
#pragma unroll
          for (int mi = 0; mi < 4; ++mi)
            acc[ni][mi] = mfma_bf16(bfr[ni], af[mi], acc[ni][mi]);
      }
    }
  }

  const int lrr = (lane >> 4) << 2;
  if (z != 2) {
    unsigned short* dst = (z == 0) ? Qo : Ko;
    const float scale = (z == 0) ? 0.125f : 1.0f;
#pragma unroll
    for (int mi = 0; mi < 4; ++mi)
#pragma unroll
      for (int ni = 0; ni < 4; ++ni)
#pragma unroll
        for (int r = 0; r < 4; ++r) {
          int m = m0 + wr * 64 + mi * 16 + lrr + r;
          int e = n0 + wc * 64 + ni * 16 + lrow;
          int b = m >> 11, s = m & (SEQ - 1);
          int h = e >> 6, dh = e & 63;
          dst[((size_t)(b * N_HEADS + h) * SEQ + s) * D_HEAD + dh] =
              f2bf(acc[mi][ni][r] * scale);
        }
  } else {
#pragma unroll
    for (int ni = 0; ni < 4; ++ni)
#pragma unroll
      for (int mi = 0; mi < 4; ++mi)
#pragma unroll
        for (int r = 0; r < 4; ++r) {
          int e = n0 + wc * 64 + ni * 16 + lrr + r;
          int m = m0 + wr * 64 + mi * 16 + lrow;
          int b = m >> 11, s = m & (SEQ - 1);
          int h = e >> 6, dh = e & 63;
          Vt[((size_t)(b * N_HEADS + h) * D_HEAD + dh) * SEQ + s] =
              f2bf(acc[ni][mi][r]);
        }
  }
}

// ---------------- flash attention with additive bias ----------------
// Swapped QK^T (mfma(K,Q)): lane holds P[k = nt*16 + (lane>>4)*4 + r][q = lane&15].
// Bias per lane: 4 consecutive k -> float4 loads, prefetched one tile ahead.
// 2-phase pipeline: stage next K/V tile at iteration top, single barrier at end.
__launch_bounds__(256, 3)
__global__ void attn_kernel(const unsigned short* __restrict__ Q,
                            const unsigned short* __restrict__ K,
                            const unsigned short* __restrict__ Vt,
                            const float* __restrict__ bias,
                            unsigned short* __restrict__ ctx) {
  __shared__ __align__(16) unsigned short Qs[64][64];
  __shared__ __align__(16) unsigned short Ks[2][64][64];
  __shared__ __align__(16) unsigned short Vs[2][64][64];
  __shared__ __align__(16) unsigned short Ps[4][16][72];

  const int bh = blockIdx.y;
  const int b = bh >> 4, h = bh & (N_HEADS - 1);
  const int q0 = blockIdx.x * 64;
  const int tid = threadIdx.x, lane = tid & 63, wv = tid >> 6;
  const int lrow = lane & 15;
  const int lgrp = lane >> 4;
  const int lk8 = lgrp << 3;
  const int lrr = lgrp << 2;

  const size_t qk_base = (size_t)bh * SEQ * D_HEAD;
  const unsigned short* Vbase = Vt + (size_t)bh * D_HEAD * SEQ;

  // prologue: stage Q + first K/V tile, preload first bias tile
  stage_swz<8192>(Q + qk_base + (size_t)q0 * D_HEAD, D_HEAD, &Qs[0][0], tid);
  stage_swz<8192>(K + qk_base, D_HEAD, &Ks[0][0][0], tid);
  stage_swz<8192>(Vbase, SEQ, &Vs[0][0][0], tid);

  const float* bp = bias + (size_t)h * SEQ * SEQ +
                    (size_t)(q0 + wv * 16 + lrow) * SEQ + lrr;
  float4 bcur[4], bnext[4];
#pragma unroll
  for (int nt = 0; nt < 4; ++nt)
    bcur[nt] = *reinterpret_cast<const float4*>(bp + nt * 16);

  __syncthreads();

  short8 qf[2];
#pragma unroll
  for (int ks = 0; ks < 2; ++ks)
    qf[ks] = frag_ld(&Qs[0][0], wv * 16 + lrow, ks * 32 + lk8);

  float m_run = -1e30f, l_run = 0.f;
  f32x4 o_acc[4];
  const f32x4 zero = {0.f, 0.f, 0.f, 0.f};
#pragma unroll
  for (int dt = 0; dt < 4; ++dt) o_acc[dt] = zero;

  for (int kt = 0; kt < 32; ++kt) {
    const int cur = kt & 1;
    // issue next tile's staging + bias loads EARLY (latency hides under compute)
    if (kt < 31) {
      const int kvn = (kt + 1) * 64;
      stage_swz<8192>(K + qk_base + (size_t)kvn * D_HEAD, D_HEAD,
                      &Ks[cur ^ 1][0][0], tid);
      stage_swz<8192>(Vbase + kvn, SEQ, &Vs[cur ^ 1][0][0], tid);
#pragma unroll
      for (int nt = 0; nt < 4; ++nt)
        bnext[nt] = *reinterpret_cast<const float4*>(bp + kvn + nt * 16);
    }

    // QK^T (swapped): s[nt] = P[k-block nt][q]
    f32x4 s[4];
#pragma unroll
    for (int nt = 0; nt < 4; ++nt) s[nt] = zero;
    __builtin_amdgcn_s_setprio(1);
#pragma unroll
    for (int ks = 0; ks < 2; ++ks)
#pragma unroll
      for (int nt = 0; nt < 4; ++nt) {
        short8 kf = frag_ld(&Ks[cur][0][0], nt * 16 + lrow, ks * 32 + lk8);
        s[nt] = mfma_bf16(kf, qf[ks], s[nt]);
      }
    __builtin_amdgcn_s_setprio(0);

    // bias add + online softmax (per lane: one q row, 16 k values)
    float p[4][4];
    float pmax = -1e30f;
#pragma unroll
    for (int nt = 0; nt < 4; ++nt)
#pragma unroll
      for (int r = 0; r < 4; ++r) {
        float v = s[nt][r] + ((const float*)&bcur[nt])[r];
        p[nt][r] = v;
        pmax = fmaxf(pmax, v);
      }
    pmax = fmaxf(pmax, __shfl_xor(pmax, 16));
    pmax = fmaxf(pmax, __shfl_xor(pmax, 32));
    float mnew = fmaxf(m_run, pmax);
    float corr = __expf(m_run - mnew);
    float rs = 0.f;
#pragma unroll
    for (int nt = 0; nt < 4; ++nt)
#pragma unroll
      for (int r = 0; r < 4; ++r) {
        float e = __expf(p[nt][r] - mnew);
        p[nt][r] = e;
        rs += e;
      }
    rs += __shfl_xor(rs, 16);
    rs += __shfl_xor(rs, 32);
    l_run = l_run * corr + rs;
    m_run = mnew;

    // P -> LDS (wave-private; 8B packed stores, k is contiguous per lane)
#pragma unroll
    for (int nt = 0; nt < 4; ++nt) {
      ushort4v pk;
#pragma unroll
      for (int r = 0; r < 4; ++r) pk[r] = f2bf(p[nt][r]);
      *reinterpret_cast<ushort4v*>(&Ps[wv][lrow][nt * 16 + lrr]) = pk;
    }

    // rescale o_acc: corr lives at lane (q&15); o_acc rows are q = lrr + r
#pragma unroll
    for (int r = 0; r < 4; ++r) {
      float c = __shfl(corr, lrr + r);
#pragma unroll
      for (int dt = 0; dt < 4; ++dt) o_acc[dt][r] *= c;
    }

    // PV: A = P rows (q = lane&15), B = Vt rows (d)
    short8 pf[2];
#pragma unroll
    for (int ks = 0; ks < 2; ++ks)
      pf[ks] = *reinterpret_cast<const short8*>(&Ps[wv][lrow][ks * 32 + lk8]);
    __builtin_amdgcn_s_setprio(1);
#pragma unroll
    for (int ks = 0; ks < 2; ++ks)
#pragma unroll
      for (int dt = 0; dt < 4; ++dt) {
        short8 vf = frag_ld(&Vs[cur][0][0], dt * 16 + lrow, ks * 32 + lk8);
        o_acc[dt] = mfma_bf16(pf[ks], vf, o_acc[dt]);
      }
    __builtin_amdgcn_s_setprio(0);

    __syncthreads();  // drains next-tile staging (vmcnt) + separates buffers
    if (kt < 31) {
#pragma unroll
      for (int nt = 0; nt < 4; ++nt) bcur[nt] = bnext[nt];
    }
  }

  // epilogue: normalize and store ctx [B,S,H*Dh]
  float inv = 1.0f / l_run;  // per lane, q = lane&15
#pragma unroll
  for (int r = 0; r < 4; ++r) {
    float invq = __shfl(inv, lrr + r);
    int qs = q0 + wv * 16 + lrr + r;
#pragma unroll
    for (int dt = 0; dt < 4; ++dt)
      ctx[((size_t)(b * SEQ) + qs) * D_MODEL + h * 64 + dt * 16 + lrow] =
          f2bf(o_acc[dt][r] * invq);
  }
}

// ---------------- output projection GEMM (+bias, fp32 out) ----------------
__launch_bounds__(256, 2)
__global__ void out_gemm(const unsigned short* __restrict__ cb,
                         const unsigned short* __restrict__ wo,
                         const float* __restrict__ bo,
                         float* __restrict__ out) {
  __shared__ __align__(16) unsigned short As[128][64];
  __shared__ __align__(16) unsigned short Bs[128][64];
  const int m0 = blockIdx.y * 128;
  const int n0 = blockIdx.x * 128;
  const int tid = threadIdx.x;
  const int lane = tid & 63;
  const int wv = tid >> 6;
  const int wr = wv >> 1, wc = wv & 1;
  const int lrow = lane & 15;
  const int lk8 = (lane >> 4) << 3;

  f32x4 acc[4][4];
  const f32x4 zero = {0.f, 0.f, 0.f, 0.f};
#pragma unroll
  for (int i = 0; i < 4; ++i)
#pragma unroll
    for (int j = 0; j < 4; ++j) acc[i][j] = zero;

  for (int k0 = 0; k0 < D_MODEL; k0 += 64) {
    __syncthreads();
    stage_swz<16384>(cb + (size_t)m0 * D_MODEL + k0, D_MODEL, &As[0][0], tid);
    stage_swz<16384>(wo + (size_t)n0 * D_MODEL + k0, D_MODEL, &Bs[0][0], tid);
    __syncthreads();
#pragma unroll
    for (int ks = 0; ks < 2; ++ks) {
      short8 af[4], bfr[4];
#pragma unroll
      for (int mi = 0; mi < 4; ++mi)
        af[mi] = frag_ld(&As[0][0], wr * 64 + mi * 16 + lrow, ks * 32 + lk8);
#pragma unroll
      for (int ni = 0; ni < 4; ++ni)
        bfr[ni] = frag_ld(&Bs[0][0], wc * 64 + ni * 16 + lrow, ks * 32 + lk8);
#pragma unroll
      for (int mi = 0; mi < 4; ++mi)
#pragma unroll
        for (int ni = 0; ni < 4; ++ni)
          acc[mi][ni] = mfma_bf16(af[mi], bfr[ni], acc[mi][ni]);
    }
  }

  const int lrr = (lane >> 4) << 2;
#pragma unroll
  for (int mi = 0; mi < 4; ++mi)
#pragma unroll
    for (int ni = 0; ni < 4; ++ni)
#pragma unroll
      for (int r = 0; r < 4; ++r) {
        int m = m0 + wr * 64 + mi * 16 + lrr + r;
        int e = n0 + wc * 64 + ni * 16 + lrow;
        out[(size_t)m * D_MODEL + e] = acc[mi][ni][r] + bo[e];
      }
}

extern "C" void kernel_launch(void* const* d_in, const int* in_sizes, int n_in,
                              void* d_out, int out_size, void* d_ws, size_t ws_size,
                              hipStream_t stream) {
  const float* x    = (const float*)d_in[0];
  const float* bias = (const float*)d_in[1];
  const float* w_q  = (const float*)d_in[2];
  const float* w_k  = (const float*)d_in[3];
  const float* w_v  = (const float*)d_in[4];
  const float* w_o  = (const float*)d_in[5];
  const float* b_o  = (const float*)d_in[6];
  float* out = (float*)d_out;

  const size_t NX = (size_t)BATCH * SEQ * D_MODEL;       // 8388608
  const size_t NW = (size_t)D_MODEL * D_MODEL;           // 1048576

  unsigned short* xb    = (unsigned short*)d_ws;
  unsigned short* wqkvb = xb + NX;
  unsigned short* wob   = wqkvb + 3 * NW;
  unsigned short* Qb    = wob + NW;
  unsigned short* Kb    = Qb + NX;
  unsigned short* Vtb   = Kb + NX;
  unsigned short* ctxb  = Vtb + NX;

  cvt_kernel<<<(int)(NX / 2048), 256, 0, stream>>>(x, xb, (int)NX);
  cvt_kernel<<<(int)(NW / 2048), 256, 0, stream>>>(w_q, wqkvb, (int)NW);
  cvt_kernel<<<(int)(NW / 2048), 256, 0, stream>>>(w_k, wqkvb + NW, (int)NW);
  cvt_kernel<<<(int)(NW / 2048), 256, 0, stream>>>(w_v, wqkvb + 2 * NW, (int)NW);
  cvt_kernel<<<(int)(NW / 2048), 256, 0, stream>>>(w_o, wob, (int)NW);

  qkv_gemm<<<dim3(8, 64, 3), 256, 0, stream>>>(xb, wqkvb, Qb, Kb, Vtb);
  attn_kernel<<<dim3(32, 64), 256, 0, stream>>>(Qb, Kb, Vtb, bias, ctxb);
  out_gemm<<<dim3(8, 64), 256, 0, stream>>>(ctxb, wob, b_o, out);
}

// Round 3
// 305.115 us; speedup vs baseline: 1.6913x; 1.1667x over previous
//
#include <hip/hip_runtime.h>
#include <hip/hip_bf16.h>

#define D_MODEL 1024
#define N_HEADS 16
#define D_HEAD  64
#define BATCH   4
#define SEQ     2048

typedef __attribute__((ext_vector_type(8))) short short8;
typedef __attribute__((ext_vector_type(8))) unsigned short ushort8;
typedef __attribute__((ext_vector_type(4))) unsigned short ushort4v;
typedef __attribute__((ext_vector_type(4))) float f32x4;

__device__ inline unsigned short f2bf(float f) {
  unsigned int u = __builtin_bit_cast(unsigned int, f);
  u += 0x7fffu + ((u >> 16) & 1u);
  return (unsigned short)(u >> 16);
}

__device__ inline f32x4 mfma_bf16(short8 a, short8 b, f32x4 c) {
  return __builtin_amdgcn_mfma_f32_16x16x32_bf16(a, b, c, 0, 0, 0);
}

// ---------------- fp32 -> bf16 conversion ----------------
__global__ void cvt_kernel(const float* __restrict__ src,
                           unsigned short* __restrict__ dst, int n) {
  int i = (blockIdx.x * 256 + threadIdx.x) * 8;
  if (i >= n) return;
  float4 a = *reinterpret_cast<const float4*>(src + i);
  float4 b = *reinterpret_cast<const float4*>(src + i + 4);
  ushort8 o;
  o[0] = f2bf(a.x); o[1] = f2bf(a.y); o[2] = f2bf(a.z); o[3] = f2bf(a.w);
  o[4] = f2bf(b.x); o[5] = f2bf(b.y); o[6] = f2bf(b.z); o[7] = f2bf(b.w);
  *reinterpret_cast<ushort8*>(dst + i) = o;
}

// ---------------- swizzled global->LDS staging ----------------
template<int NBYTES>
__device__ inline void stage_swz(const unsigned short* g0, int g_stride_elems,
                                 unsigned short* lds0, int tid) {
#pragma unroll
  for (int it = 0; it < NBYTES / 4096; ++it) {
    int o = it * 4096 + tid * 16;
    int r = o >> 7;
    int cb = (o & 127) ^ ((r & 7) << 4);
    unsigned short* g = const_cast<unsigned short*>(g0) +
                        (size_t)r * g_stride_elems + (cb >> 1);
    unsigned short* l = lds0 + (o >> 1);
    __builtin_amdgcn_global_load_lds((__attribute__((address_space(1))) void*)g,
                                     (__attribute__((address_space(3))) void*)l,
                                     16, 0, 0);
  }
}

// swizzled LDS fragment read (16B): row-stride fixed 128B
__device__ inline short8 frag_ld(const unsigned short* tile, int row, int col_el) {
  int cb = (col_el << 1) ^ ((row & 7) << 4);
  return *reinterpret_cast<const short8*>(
      reinterpret_cast<const char*>(tile) + row * 128 + cb);
}

// ---------------- QKV projection GEMM ----------------
__launch_bounds__(256, 2)
__global__ void qkv_gemm(const unsigned short* __restrict__ xb,
                         const unsigned short* __restrict__ wb,
                         unsigned short* __restrict__ Qo,
                         unsigned short* __restrict__ Ko,
                         unsigned short* __restrict__ Vt) {
  __shared__ __align__(16) unsigned short As[128][64];
  __shared__ __align__(16) unsigned short Bs[128][64];
  const int z = blockIdx.z;
  const int m0 = blockIdx.y * 128;
  const int n0 = blockIdx.x * 128;
  const int tid = threadIdx.x;
  const int lane = tid & 63;
  const int wv = tid >> 6;
  const int wr = wv >> 1, wc = wv & 1;
  const int lrow = lane & 15;
  const int lk8 = (lane >> 4) << 3;
  const unsigned short* w = wb + (size_t)z * D_MODEL * D_MODEL;

  f32x4 acc[4][4];
  const f32x4 zero = {0.f, 0.f, 0.f, 0.f};
#pragma unroll
  for (int i = 0; i < 4; ++i)
#pragma unroll
    for (int j = 0; j < 4; ++j) acc[i][j] = zero;

  for (int k0 = 0; k0 < D_MODEL; k0 += 64) {
    __syncthreads();
    stage_swz<16384>(xb + (size_t)m0 * D_MODEL + k0, D_MODEL, &As[0][0], tid);
    stage_swz<16384>(w  + (size_t)n0 * D_MODEL + k0, D_MODEL, &Bs[0][0], tid);
    __syncthreads();
#pragma unroll
    for (int ks = 0; ks < 2; ++ks) {
      short8 af[4], bfr[4];
#pragma unroll
      for (int mi = 0; mi < 4; ++mi)
        af[mi] = frag_ld(&As[0][0], wr * 64 + mi * 16 + lrow, ks * 32 + lk8);
#pragma unroll
      for (int ni = 0; ni < 4; ++ni)
        bfr[ni] = frag_ld(&Bs[0][0], wc * 64 + ni * 16 + lrow, ks * 32 + lk8);
      if (z != 2) {
#pragma unroll
        for (int mi = 0; mi < 4; ++mi)
#pragma unroll
          for (int ni = 0; ni < 4; ++ni)
            acc[mi][ni] = mfma_bf16(af[mi], bfr[ni], acc[mi][ni]);
      } else {
#pragma unroll
        for (int ni = 0; ni < 4; ++ni)
#pragma unroll
          for (int mi = 0; mi < 4; ++mi)
            acc[ni][mi] = mfma_bf16(bfr[ni], af[mi], acc[ni][mi]);
      }
    }
  }

  const int lrr = (lane >> 4) << 2;
  if (z != 2) {
    unsigned short* dst = (z == 0) ? Qo : Ko;
    const float scale = (z == 0) ? 0.125f : 1.0f;
#pragma unroll
    for (int mi = 0; mi < 4; ++mi)
#pragma unroll
      for (int ni = 0; ni < 4; ++ni)
#pragma unroll
        for (int r = 0; r < 4; ++r) {
          int m = m0 + wr * 64 + mi * 16 + lrr + r;
          int e = n0 + wc * 64 + ni * 16 + lrow;
          int b = m >> 11, s = m & (SEQ - 1);
          int h = e >> 6, dh = e & 63;
          dst[((size_t)(b * N_HEADS + h) * SEQ + s) * D_HEAD + dh] =
              f2bf(acc[mi][ni][r] * scale);
        }
  } else {
#pragma unroll
    for (int ni = 0; ni < 4; ++ni)
#pragma unroll
      for (int mi = 0; mi < 4; ++mi)
#pragma unroll
        for (int r = 0; r < 4; ++r) {
          int e = n0 + wc * 64 + ni * 16 + lrr + r;
          int m = m0 + wr * 64 + mi * 16 + lrow;
          int b = m >> 11, s = m & (SEQ - 1);
          int h = e >> 6, dh = e & 63;
          Vt[((size_t)(b * N_HEADS + h) * D_HEAD + dh) * SEQ + s] =
              f2bf(acc[ni][mi][r]);
        }
  }
}

// ---------------- flash attention, batch-fused per block ----------------
// One block = (64-row q-tile, head h); loops b=0..3 in registers so the bias
// float4s (batch-invariant) are loaded ONCE per kv-tile and reused 4x.
// Flattened (kt,b) 2-phase LDS pipeline, inner b fully unrolled (static idx).
__launch_bounds__(256, 2)
__global__ void attn_kernel(const unsigned short* __restrict__ Q,
                            const unsigned short* __restrict__ K,
                            const unsigned short* __restrict__ Vt,
                            const float* __restrict__ bias,
                            unsigned short* __restrict__ ctx) {
  __shared__ __align__(16) unsigned short Qs[64][64];
  __shared__ __align__(16) unsigned short Ks[2][64][64];
  __shared__ __align__(16) unsigned short Vs[2][64][64];
  __shared__ __align__(16) unsigned short Ps[4][16][72];

  // XCD-swizzled mapping: same-h blocks co-locate on one XCD for K/V L2 reuse
  const int fid = blockIdx.y * 32 + blockIdx.x;   // grid (32, 16)
  const int j = fid >> 3;
  const int h = (fid & 7) + 8 * (j & 1);
  const int q0 = (j >> 1) * 64;

  const int tid = threadIdx.x, lane = tid & 63, wv = tid >> 6;
  const int lrow = lane & 15;
  const int lgrp = lane >> 4;
  const int lk8 = lgrp << 3;
  const int lrr = lgrp << 2;

  // per-batch Q fragments (staged sequentially through one LDS buffer)
  short8 qf[4][2];
#pragma unroll
  for (int b = 0; b < 4; ++b) {
    stage_swz<8192>(Q + ((size_t)(b * N_HEADS + h) * SEQ + q0) * D_HEAD,
                    D_HEAD, &Qs[0][0], tid);
    __syncthreads();
#pragma unroll
    for (int ks = 0; ks < 2; ++ks)
      qf[b][ks] = frag_ld(&Qs[0][0], wv * 16 + lrow, ks * 32 + lk8);
    __syncthreads();
  }

  // stage first step (kt=0, b=0)
  stage_swz<8192>(K + (size_t)h * SEQ * D_HEAD, D_HEAD, &Ks[0][0][0], tid);
  stage_swz<8192>(Vt + (size_t)h * D_HEAD * SEQ, SEQ, &Vs[0][0][0], tid);

  // bias: per lane q = q0+wv*16+lrow, k = kt*64 + nt*16 + lrr + {0..3}
  const float* bp = bias + (size_t)h * SEQ * SEQ +
                    (size_t)(q0 + wv * 16 + lrow) * SEQ + lrr;
  f32x4 bcur[4], bnext[4];
#pragma unroll
  for (int nt = 0; nt < 4; ++nt)
    bcur[nt] = __builtin_nontemporal_load(
        reinterpret_cast<const f32x4*>(bp + nt * 16));

  float m_run[4], l_run[4];
  f32x4 o_acc[4][4];
  const f32x4 zero = {0.f, 0.f, 0.f, 0.f};
#pragma unroll
  for (int b = 0; b < 4; ++b) {
    m_run[b] = -1e30f; l_run[b] = 0.f;
#pragma unroll
    for (int dt = 0; dt < 4; ++dt) o_acc[b][dt] = zero;
  }

  __syncthreads();

  for (int kt = 0; kt < 32; ++kt) {
    // prefetch next kv-tile's bias (used 4 steps from now)
    if (kt < 31) {
#pragma unroll
      for (int nt = 0; nt < 4; ++nt)
        bnext[nt] = __builtin_nontemporal_load(
            reinterpret_cast<const f32x4*>(bp + (kt + 1) * 64 + nt * 16));
    }

#pragma unroll
    for (int b = 0; b < 4; ++b) {
      const int cur = b & 1;  // step parity (4 steps/kt keeps parity aligned)

      // stage next step's K/V early (hides under this step's compute)
      if (!(kt == 31 && b == 3)) {
        const int nb = (b + 1) & 3;
        const int nkt = kt + (b == 3 ? 1 : 0);
        stage_swz<8192>(K + (size_t)(nb * N_HEADS + h) * SEQ * D_HEAD +
                            (size_t)nkt * 64 * D_HEAD,
                        D_HEAD, &Ks[cur ^ 1][0][0], tid);
        stage_swz<8192>(Vt + (size_t)(nb * N_HEADS + h) * D_HEAD * SEQ +
                            nkt * 64,
                        SEQ, &Vs[cur ^ 1][0][0], tid);
      }

      // QK^T (swapped): lane holds P[k = nt*16+lrr+r][q = lrow]
      f32x4 s[4];
#pragma unroll
      for (int nt = 0; nt < 4; ++nt) s[nt] = zero;
      __builtin_amdgcn_s_setprio(1);
#pragma unroll
      for (int ks = 0; ks < 2; ++ks)
#pragma unroll
        for (int nt = 0; nt < 4; ++nt) {
          short8 kf = frag_ld(&Ks[cur][0][0], nt * 16 + lrow, ks * 32 + lk8);
          s[nt] = mfma_bf16(kf, qf[b][ks], s[nt]);
        }
      __builtin_amdgcn_s_setprio(0);

      // bias add + online softmax
      float p[4][4];
      float pmax = -1e30f;
#pragma unroll
      for (int nt = 0; nt < 4; ++nt)
#pragma unroll
        for (int r = 0; r < 4; ++r) {
          float v = s[nt][r] + bcur[nt][r];
          p[nt][r] = v;
          pmax = fmaxf(pmax, v);
        }
      pmax = fmaxf(pmax, __shfl_xor(pmax, 16));
      pmax = fmaxf(pmax, __shfl_xor(pmax, 32));
      float mnew = fmaxf(m_run[b], pmax);
      float corr = __expf(m_run[b] - mnew);
      float rs = 0.f;
#pragma unroll
      for (int nt = 0; nt < 4; ++nt)
#pragma unroll
        for (int r = 0; r < 4; ++r) {
          float e = __expf(p[nt][r] - mnew);
          p[nt][r] = e;
          rs += e;
        }
      rs += __shfl_xor(rs, 16);
      rs += __shfl_xor(rs, 32);
      l_run[b] = l_run[b] * corr + rs;
      m_run[b] = mnew;

      // P -> LDS (wave-private, 8B packed stores)
#pragma unroll
      for (int nt = 0; nt < 4; ++nt) {
        ushort4v pk;
#pragma unroll
        for (int r = 0; r < 4; ++r) pk[r] = f2bf(p[nt][r]);
        *reinterpret_cast<ushort4v*>(&Ps[wv][lrow][nt * 16 + lrr]) = pk;
      }

      // rescale o_acc: corr lives at lane q=lrow; o_acc rows are q = lrr+r
#pragma unroll
      for (int r = 0; r < 4; ++r) {
        float c = __shfl(corr, lrr + r);
#pragma unroll
        for (int dt = 0; dt < 4; ++dt) o_acc[b][dt][r] *= c;
      }

      // PV: A = P rows (q = lrow), B = Vt rows (d)
      short8 pf[2];
#pragma unroll
      for (int ks = 0; ks < 2; ++ks)
        pf[ks] = *reinterpret_cast<const short8*>(&Ps[wv][lrow][ks * 32 + lk8]);
      __builtin_amdgcn_s_setprio(1);
#pragma unroll
      for (int ks = 0; ks < 2; ++ks)
#pragma unroll
        for (int dt = 0; dt < 4; ++dt) {
          short8 vf = frag_ld(&Vs[cur][0][0], dt * 16 + lrow, ks * 32 + lk8);
          o_acc[b][dt] = mfma_bf16(pf[ks], vf, o_acc[b][dt]);
        }
      __builtin_amdgcn_s_setprio(0);

      __syncthreads();  // drains this wave's staging DMA + swaps buffers
    }

    if (kt < 31) {
#pragma unroll
      for (int nt = 0; nt < 4; ++nt) bcur[nt] = bnext[nt];
    }
  }

  // epilogue: normalize and store ctx [B,S,D_MODEL]
#pragma unroll
  for (int b = 0; b < 4; ++b) {
    float inv = 1.0f / l_run[b];
#pragma unroll
    for (int r = 0; r < 4; ++r) {
      float invq = __shfl(inv, lrr + r);
      int qs = q0 + wv * 16 + lrr + r;
#pragma unroll
      for (int dt = 0; dt < 4; ++dt)
        ctx[((size_t)b * SEQ + qs) * D_MODEL + h * 64 + dt * 16 + lrow] =
            f2bf(o_acc[b][dt][r] * invq);
    }
  }
}

// ---------------- output projection GEMM (+bias, fp32 out) ----------------
__launch_bounds__(256, 2)
__global__ void out_gemm(const unsigned short* __restrict__ cb,
                         const unsigned short* __restrict__ wo,
                         const float* __restrict__ bo,
                         float* __restrict__ out) {
  __shared__ __align__(16) unsigned short As[128][64];
  __shared__ __align__(16) unsigned short Bs[128][64];
  const int m0 = blockIdx.y * 128;
  const int n0 = blockIdx.x * 128;
  const int tid = threadIdx.x;
  const int lane = tid & 63;
  const int wv = tid >> 6;
  const int wr = wv >> 1, wc = wv & 1;
  const int lrow = lane & 15;
  const int lk8 = (lane >> 4) << 3;

  f32x4 acc[4][4];
  const f32x4 zero = {0.f, 0.f, 0.f, 0.f};
#pragma unroll
  for (int i = 0; i < 4; ++i)
#pragma unroll
    for (int j = 0; j < 4; ++j) acc[i][j] = zero;

  for (int k0 = 0; k0 < D_MODEL; k0 += 64) {
    __syncthreads();
    stage_swz<16384>(cb + (size_t)m0 * D_MODEL + k0, D_MODEL, &As[0][0], tid);
    stage_swz<16384>(wo + (size_t)n0 * D_MODEL + k0, D_MODEL, &Bs[0][0], tid);
    __syncthreads();
#pragma unroll
    for (int ks = 0; ks < 2; ++ks) {
      short8 af[4], bfr[4];
#pragma unroll
      for (int mi = 0; mi < 4; ++mi)
        af[mi] = frag_ld(&As[0][0], wr * 64 + mi * 16 + lrow, ks * 32 + lk8);
#pragma unroll
      for (int ni = 0; ni < 4; ++ni)
        bfr[ni] = frag_ld(&Bs[0][0], wc * 64 + ni * 16 + lrow, ks * 32 + lk8);
#pragma unroll
      for (int mi = 0; mi < 4; ++mi)
#pragma unroll
        for (int ni = 0; ni < 4; ++ni)
          acc[mi][ni] = mfma_bf16(af[mi], bfr[ni], acc[mi][ni]);
    }
  }

  const int lrr = (lane >> 4) << 2;
#pragma unroll
  for (int mi = 0; mi < 4; ++mi)
#pragma unroll
    for (int ni = 0; ni < 4; ++ni)
#pragma unroll
      for (int r = 0; r < 4; ++r) {
        int m = m0 + wr * 64 + mi * 16 + lrr + r;
        int e = n0 + wc * 64 + ni * 16 + lrow;
        out[(size_t)m * D_MODEL + e] = acc[mi][ni][r] + bo[e];
      }
}

extern "C" void kernel_launch(void* const* d_in, const int* in_sizes, int n_in,
                              void* d_out, int out_size, void* d_ws, size_t ws_size,
                              hipStream_t stream) {
  const float* x    = (const float*)d_in[0];
  const float* bias = (const float*)d_in[1];
  const float* w_q  = (const float*)d_in[2];
  const float* w_k  = (const float*)d_in[3];
  const float* w_v  = (const float*)d_in[4];
  const float* w_o  = (const float*)d_in[5];
  const float* b_o  = (const float*)d_in[6];
  float* out = (float*)d_out;

  const size_t NX = (size_t)BATCH * SEQ * D_MODEL;       // 8388608
  const size_t NW = (size_t)D_MODEL * D_MODEL;           // 1048576

  unsigned short* xb    = (unsigned short*)d_ws;
  unsigned short* wqkvb = xb + NX;
  unsigned short* wob   = wqkvb + 3 * NW;
  unsigned short* Qb    = wob + NW;
  unsigned short* Kb    = Qb + NX;
  unsigned short* Vtb   = Kb + NX;
  unsigned short* ctxb  = Vtb + NX;

  cvt_kernel<<<(int)(NX / 2048), 256, 0, stream>>>(x, xb, (int)NX);
  cvt_kernel<<<(int)(NW / 2048), 256, 0, stream>>>(w_q, wqkvb, (int)NW);
  cvt_kernel<<<(int)(NW / 2048), 256, 0, stream>>>(w_k, wqkvb + NW, (int)NW);
  cvt_kernel<<<(int)(NW / 2048), 256, 0, stream>>>(w_v, wqkvb + 2 * NW, (int)NW);
  cvt_kernel<<<(int)(NW / 2048), 256, 0, stream>>>(w_o, wob, (int)NW);

  qkv_gemm<<<dim3(8, 64, 3), 256, 0, stream>>>(xb, wqkvb, Qb, Kb, Vtb);
  attn_kernel<<<dim3(32, 16), 256, 0, stream>>>(Qb, Kb, Vtb, bias, ctxb);
  out_gemm<<<dim3(8, 64), 256, 0, stream>>>(ctxb, wob, b_o, out);
}